// Round 8
// baseline (413.485 us; speedup 1.0000x reference)
//
#include <hip/hip_runtime.h>
#include <hip/hip_fp16.h>

// Softmax attention (mask is a no-op). B=4, S=4096, D=256, fp32 in/out.
// Round 8: 2 waves/SIMD, placement-proof. r4/r6 proved block->XCD placement
// changes off the 256thr/1-per-CU config, so attn6 reads the PHYSICAL XCD id
// (s_getreg HW_REG_XCC_ID, HW-verified) and self-assigns (b,split,qi) from
// per-XCD atomicCAS queues -> KV flocking holds under ANY placement.
//  - grid 512 x 256 thr, tile=32 dbuf (LDS 64KB) -> 2 blocks/CU, 2 waves/SIMD
//  - split-K=4: 16 groups, 2 per XCD (2MB KV streams, fit 4MB L2)
//  - per-wave math = r7-validated swapped 32x32 MFMA, in-register softmax
//  - VALU cuts: fmax/sum trees, raw v_exp_f32
//  - proj: V output single-term (x_h*W_h), Q/K keep 3-term hi/lo

typedef _Float16 f16x8 __attribute__((ext_vector_type(8)));
typedef _Float16 f16x4 __attribute__((ext_vector_type(4)));
typedef float    f32x4 __attribute__((ext_vector_type(4)));
typedef float    f32x16 __attribute__((ext_vector_type(16)));

#define MFMA16(A, B, C) __builtin_amdgcn_mfma_f32_16x16x32_f16((A), (B), (C), 0, 0, 0)
#define MFMA32(A, B, C) __builtin_amdgcn_mfma_f32_32x32x16_f16((A), (B), (C), 0, 0, 0)

static __device__ __forceinline__ void gload16(const _Float16* g, _Float16* l) {
    __builtin_amdgcn_global_load_lds(
        (unsigned int __attribute__((address_space(1)))*)g,
        (unsigned int __attribute__((address_space(3)))*)l, 16, 0, 0);
}

static __device__ __forceinline__ unsigned packh(float a, float b) {
    union { _Float16 h[2]; unsigned u; } x;
    x.h[0] = (_Float16)a; x.h[1] = (_Float16)b;
    return x.u;
}

static __device__ __forceinline__ float fexp2(float x) {
    float r;
    asm("v_exp_f32 %0, %1" : "=v"(r) : "v"(x));
    return r;
}

// ---------------- kernel Z: zero the 8 per-XCD work counters ----------------
__global__ void zero_cnt_kernel(int* cnt) { cnt[threadIdx.x] = 0; }

// ---------------- kernel 0: x -> fp16 hi/lo, FRAGMENT-LINEAR (r7) -----------
__global__ __launch_bounds__(256) void convert_x_kernel(
    const float* __restrict__ x, _Float16* __restrict__ xh, _Float16* __restrict__ xl)
{
    int i = blockIdx.x * 256 + threadIdx.x;
    int e = i * 4;
    int row = e >> 8, k = e & 255;
    float4 v = ((const float4*)x)[i];
    float vv[4] = {v.x, v.y, v.z, v.w};
    f16x4 h, l;
#pragma unroll
    for (int j = 0; j < 4; ++j) {
        _Float16 hh = (_Float16)vv[j];
        h[j] = hh; l[j] = (_Float16)(vv[j] - (float)hh);
    }
    const int lane = (row & 15) + 16 * ((k >> 3) & 3);
    const int dst = (((row >> 4) * 8 + (k >> 5)) * 64 + lane) * 8 + (k & 7);
    *(f16x4*)(xh + dst) = h;
    *(f16x4*)(xl + dst) = l;
}

// ---------------- kernel 1: W -> W^T hi/lo, FRAGMENT-LINEAR (r7) ------------
__global__ __launch_bounds__(256) void convert_w_kernel(
    const float* __restrict__ Wq, const float* __restrict__ Wk, const float* __restrict__ Wv,
    _Float16* __restrict__ Wth, _Float16* __restrict__ Wtl)
{
    int idx = blockIdx.x * 256 + threadIdx.x;
    int mat = idx >> 16, e = idx & 65535;
    int k = e >> 8, n = e & 255;
    const float* W = (mat == 0) ? Wq : (mat == 1) ? Wk : Wv;
    float v = W[e];
    _Float16 h = (_Float16)v;
    _Float16 lo = (_Float16)(v - (float)h);
    const int lane = (n & 15) + 16 * ((k >> 3) & 3);
    const int dst = mat * 65536 + (((k >> 5) * 16 + (n >> 4)) * 64 + lane) * 8 + (k & 7);
    Wth[dst] = h;
    Wtl[dst] = lo;
}

// ---------------- kernel 2: projections (r7 + V single-term) ----------------
__global__ __launch_bounds__(256) void proj_kernel(
    const _Float16* __restrict__ xh, const _Float16* __restrict__ xl,
    const _Float16* __restrict__ Wth, const _Float16* __restrict__ Wtl,
    const float* __restrict__ bq, const float* __restrict__ bk, const float* __restrict__ bv,
    _Float16* __restrict__ Qf, _Float16* __restrict__ Kf, _Float16* __restrict__ Vt)
{
    const int mat = blockIdx.y;
    const int tid = threadIdx.x, wid = tid >> 6, lane = tid & 63;
    const int lrow = lane & 15, lgrp = lane >> 4;
    const int rb = blockIdx.x * 4 + wid;
    const int row0 = rb * 16;
    const _Float16* Wh = Wth + mat * 65536;
    const _Float16* Wl = Wtl + mat * 65536;
    const float* bias = (mat == 0) ? bq : (mat == 1) ? bk : bv;

    f32x4 acc[16];
#pragma unroll
    for (int i = 0; i < 16; ++i) acc[i] = f32x4{0.f, 0.f, 0.f, 0.f};

#pragma unroll
    for (int ks = 0; ks < 8; ++ks) {
        const size_t abase = (((size_t)rb * 8 + ks) * 64 + lane) * 8;
        f16x8 Ah = *(const f16x8*)(xh + abase);
        f16x8 Al = *(const f16x8*)(xl + abase);
#pragma unroll
        for (int nt = 0; nt < 16; ++nt) {
            const size_t bbase = ((ks * 16 + nt) * 64 + lane) * 8;
            f16x8 Bh = *(const f16x8*)(Wh + bbase);
            acc[nt] = MFMA16(Ah, Bh, acc[nt]);
            if (mat != 2) {   // V needs only the hi*hi term (err ~6e-4)
                f16x8 Bl = *(const f16x8*)(Wl + bbase);
                acc[nt] = MFMA16(Al, Bh, acc[nt]);
                acc[nt] = MFMA16(Ah, Bl, acc[nt]);
            }
        }
    }

    const float LOG2E = 1.4426950408889634f;
#pragma unroll
    for (int nt = 0; nt < 16; ++nt) {
        const int n = nt * 16 + lrow;
        const float bb = bias[n];
        if (mat == 2) {
            const int m0 = row0 + lgrp * 4;
            f16x4 vv;
#pragma unroll
            for (int r = 0; r < 4; ++r) vv[r] = (_Float16)(acc[nt][r] + bb);
            *(f16x4*)(Vt + (size_t)n * 16384 + m0) = vv;
        } else {
            _Float16* dst = (mat == 0) ? Qf : Kf;
            const float s = (mat == 0) ? LOG2E : 1.0f;
#pragma unroll
            for (int r = 0; r < 4; ++r) {
                const int grow = row0 + lgrp * 4 + r;
                dst[(size_t)grow * 256 + n] = (_Float16)((acc[nt][r] + bb) * s);
            }
        }
    }
}

// -------- kernel 3: attn6 — self-assigned XCD queues, 2 blocks/CU -----------
// 512 blocks x 256 thr. Work item = (group [0,16), qi [0,32)); group = 2*xcd+sub.
// Per wave: 32 q x 1024 keys (split-K=4), tile 32 keys, K/V double-buffered.
__global__ __launch_bounds__(256, 2) void attn6_kernel(
    const _Float16* __restrict__ Qf, const _Float16* __restrict__ Kf,
    const _Float16* __restrict__ Vt, _Float16* __restrict__ Op01,
    _Float16* __restrict__ Op23, float* __restrict__ ml, int* __restrict__ cnt)
{
    __shared__ _Float16 Kb[2][32 * 256];   // [key][d] 512B rows, 16KB/buf
    __shared__ _Float16 Vb[2][256 * 32];   // [d][key] 64B rows,  16KB/buf
    __shared__ int s_item;

    const int tid = threadIdx.x, wid = tid >> 6, lane = tid & 63;
    const int lq = lane & 31, hi = lane >> 5;

    if (tid == 0) {
        int xcd;
        asm volatile("s_getreg_b32 %0, hwreg(HW_REG_XCC_ID)" : "=s"(xcd));
        xcd &= 7;
        int item = -1;
#pragma unroll 1
        for (int k = 0; k < 8 && item < 0; ++k) {
            int* q = cnt + ((xcd + k) & 7);
            int v = atomicAdd(q, 0);            // read
            while (v < 64) {                    // CAS-grab (no over-increment)
                int old = atomicCAS(q, v, v + 1);
                if (old == v) { item = ((xcd + k) & 7) * 64 + v; break; }
                v = old;
            }
        }
        s_item = item;
    }
    __syncthreads();
    const int item = s_item;
    const int group = (item >> 6) * 2 + ((item & 63) >> 5);  // [0,16)
    const int qi = item & 31;
    const int b = group >> 2, split = group & 3;
    const size_t bS = (size_t)b * 4096;
    const size_t qrow = bS + qi * 128 + wid * 32;
    const size_t k0g = bS + (size_t)split * 1024;
    const int NT = 32;                                       // 1024 / 32

    // Q as B-fragments: lane holds Q[q=lq][d = ks*16 + hi*8 .. +8]
    f16x8 QB[16];
#pragma unroll
    for (int ks = 0; ks < 16; ++ks)
        QB[ks] = *(const f16x8*)(Qf + (qrow + lq) * 256 + ks * 16 + hi * 8);

    f32x16 Oacc[8];
#pragma unroll
    for (int i = 0; i < 8; ++i)
#pragma unroll
        for (int r = 0; r < 16; ++r) Oacc[i][r] = 0.f;
    float m_r = -1e30f, l_r = 0.f;

    auto stage = [&](int buf, int t) {
        const size_t krow = k0g + (size_t)t * 32;
#pragma unroll
        for (int it = 0; it < 4; ++it) {   // K: 1024 slots, 5-bit XOR swz src
            const int s = it * 256 + tid;
            const int row = s >> 5, c = s & 31;
            const int src = c ^ (row & 7) ^ (((row >> 3) & 3) << 3);
            gload16(Kf + (krow + row) * 256 + src * 8, &Kb[buf][s * 8]);
        }
#pragma unroll
        for (int it = 0; it < 4; ++it) {   // V^T: 1024 slots, 2-bit XOR swz
            const int s = it * 256 + tid;
            const int d = s >> 2, c = s & 3;
            gload16(Vt + (size_t)d * 16384 + krow + ((c ^ ((d >> 1) & 3)) * 8), &Vb[buf][s * 8]);
        }
    };

    stage(0, 0);
    asm volatile("s_waitcnt vmcnt(0)" ::: "memory");
    __builtin_amdgcn_s_barrier();

    const float THR = 10.0f;
    const int kx = (lq & 7) ^ (((lq >> 3) & 3) << 3);   // K-read slot XOR
    const int vx = (lq >> 1) & 3;                       // V-read slot XOR
    int buf = 0;
    for (int t = 0; t < NT; ++t) {
        if (t + 1 < NT) stage(buf ^ 1, t + 1);
        const _Float16* K_ = Kb[buf];
        const _Float16* V_ = Vb[buf];

        // ---- QK: S^T[key=lq][q col], 16 MFMAs ----
        f32x16 sc;
#pragma unroll
        for (int r = 0; r < 16; ++r) sc[r] = 0.f;
#pragma unroll
        for (int ks = 0; ks < 16; ++ks) {
            const int slot = (2 * ks + hi) ^ kx;
            f16x8 Ak = *(const f16x8*)((const char*)K_ + lq * 512 + slot * 16);
            sc = MFMA32(Ak, QB[ks], sc);
        }

        // ---- per-lane online softmax (lane owns q = lq) ----
        float tm[8];
#pragma unroll
        for (int j = 0; j < 8; ++j) tm[j] = fmaxf(sc[j], sc[j + 8]);
#pragma unroll
        for (int s = 4; s > 0; s >>= 1)
#pragma unroll
            for (int j = 0; j < s; ++j) tm[j] = fmaxf(tm[j], tm[j + s]);
        float mx = fmaxf(tm[0], __shfl_xor(tm[0], 32));
        if (__any(mx > m_r + THR)) {
            const float mn = fmaxf(m_r, mx);
            const float scl = fexp2(m_r - mn);
            m_r = mn; l_r *= scl;
#pragma unroll
            for (int i = 0; i < 8; ++i)
#pragma unroll
                for (int r = 0; r < 16; ++r) Oacc[i][r] *= scl;
        }

        // ---- P = exp2(sc - m_r); sum tree; pack to PV B-frags ----
        float p[16];
#pragma unroll
        for (int r = 0; r < 16; ++r) p[r] = fexp2(sc[r] - m_r);
        float ts[8];
#pragma unroll
        for (int j = 0; j < 8; ++j) ts[j] = p[j] + p[j + 8];
#pragma unroll
        for (int s = 4; s > 0; s >>= 1)
#pragma unroll
            for (int j = 0; j < s; ++j) ts[j] += ts[j + s];
        l_r += ts[0] + __shfl_xor(ts[0], 32);

        unsigned w[8], pw[8];
#pragma unroll
        for (int j = 0; j < 8; ++j) {
            w[j] = packh(p[2 * j], p[2 * j + 1]);
            pw[j] = __shfl_xor(w[j], 32);
        }
        f16x8 Pfrag[2];
#pragma unroll
        for (int s = 0; s < 2; ++s) {
            unsigned f0 = hi ? pw[4 * s + 2] : w[4 * s + 0];
            unsigned f1 = hi ? pw[4 * s + 3] : w[4 * s + 1];
            unsigned f2 = hi ? w[4 * s + 2] : pw[4 * s + 0];
            unsigned f3 = hi ? w[4 * s + 3] : pw[4 * s + 1];
            union { unsigned u[4]; f16x8 f; } cvt;
            cvt.u[0] = f0; cvt.u[1] = f1; cvt.u[2] = f2; cvt.u[3] = f3;
            Pfrag[s] = cvt.f;
        }

        // ---- PV: O^T[d][q] += V^T.P, 16 MFMAs ----
#pragma unroll
        for (int dblk = 0; dblk < 8; ++dblk) {
#pragma unroll
            for (int kstep = 0; kstep < 2; ++kstep) {
                const int slot = (kstep * 2 + hi) ^ vx;
                f16x8 Av = *(const f16x8*)((const char*)V_ + (dblk * 32 + lq) * 64 + slot * 16);
                Oacc[dblk] = MFMA32(Av, Pfrag[kstep], Oacc[dblk]);
            }
        }

        asm volatile("s_waitcnt vmcnt(0)" ::: "memory");
        __builtin_amdgcn_s_barrier();
        buf ^= 1;
    }

    // ---- epilogue: lane owns q = qrow + lq ----
    _Float16* Ops = (split < 2) ? (Op01 + (size_t)split * 4194304)
                                : (Op23 + (size_t)(split - 2) * 4194304);
    const float inv = 1.0f / l_r;
    const size_t grow = qrow + lq;
#pragma unroll
    for (int dblk = 0; dblk < 8; ++dblk)
#pragma unroll
        for (int quad = 0; quad < 4; ++quad) {
            f16x4 o;
#pragma unroll
            for (int j = 0; j < 4; ++j) o[j] = (_Float16)(Oacc[dblk][quad * 4 + j] * inv);
            *(f16x4*)(Ops + grow * 256 + dblk * 32 + 8 * quad + 4 * hi) = o;
        }
    if (hi == 0) {
        ml[((size_t)split * 16384 + grow) * 2]     = m_r;
        ml[((size_t)split * 16384 + grow) * 2 + 1] = l_r;
    }
}

// ---------------- kernel 4: combine split-K partials (NS=4, r4-validated) ---
__global__ __launch_bounds__(256) void combine_kernel(
    const _Float16* __restrict__ Op01, const _Float16* __restrict__ Op23,
    const float* __restrict__ ml, float* __restrict__ out)
{
    const int idx = blockIdx.x * 256 + threadIdx.x;
    const int row = idx >> 2, dq = (idx & 3) * 64;
    float m_s[4], l_s[4], w[4];
    float M = -1e30f;
#pragma unroll
    for (int s = 0; s < 4; ++s) {
        m_s[s] = ml[((size_t)s * 16384 + row) * 2];
        l_s[s] = ml[((size_t)s * 16384 + row) * 2 + 1];
        M = fmaxf(M, m_s[s]);
    }
    float Wsum = 0.f;
#pragma unroll
    for (int s = 0; s < 4; ++s) { w[s] = l_s[s] * fexp2(m_s[s] - M); Wsum += w[s]; }
    const float inv = 1.0f / Wsum;
#pragma unroll
    for (int s = 0; s < 4; ++s) w[s] *= inv;

#pragma unroll
    for (int ch = 0; ch < 8; ++ch) {
        const int d0 = dq + ch * 8;
        float acc[8] = {0.f, 0.f, 0.f, 0.f, 0.f, 0.f, 0.f, 0.f};
#pragma unroll
        for (int s = 0; s < 4; ++s) {
            const _Float16* Op = (s < 2) ? (Op01 + (size_t)s * 4194304)
                                         : (Op23 + (size_t)(s - 2) * 4194304);
            f16x8 v = *(const f16x8*)(Op + (size_t)row * 256 + d0);
#pragma unroll
            for (int j = 0; j < 8; ++j) acc[j] += w[s] * (float)v[j];
        }
        float4 o0 = {acc[0], acc[1], acc[2], acc[3]};
        float4 o1 = {acc[4], acc[5], acc[6], acc[7]};
        *(float4*)(out + (size_t)row * 256 + d0) = o0;
        *(float4*)(out + (size_t)row * 256 + d0 + 4) = o1;
    }
}

extern "C" void kernel_launch(void* const* d_in, const int* in_sizes, int n_in,
                              void* d_out, int out_size, void* d_ws, size_t ws_size,
                              hipStream_t stream) {
    const float* x  = (const float*)d_in[0];
    const float* Wq = (const float*)d_in[1];
    const float* bq = (const float*)d_in[2];
    const float* Wk = (const float*)d_in[3];
    const float* bk = (const float*)d_in[4];
    const float* Wv = (const float*)d_in[5];
    const float* bv = (const float*)d_in[6];
    float* out = (float*)d_out;

    // ws: xh/xl (reused as Op splits 0/1) | Qf | Kf | Vt | W | ml | Op23 | cnt
    _Float16* xh  = (_Float16*)d_ws;
    _Float16* xl  = xh  + 4194304;
    _Float16* Qf  = xl  + 4194304;
    _Float16* Kf  = Qf  + 4194304;
    _Float16* Vt  = Kf  + 4194304;
    _Float16* Wth = Vt  + 4194304;
    _Float16* Wtl = Wth + 196608;
    float*    ml  = (float*)(Wtl + 196608);            // 4*16384*2 f32 = 512KB
    _Float16* Op23 = (_Float16*)((char*)ml + 524288);  // splits 2,3 (16MB)
    int*      cnt = (int*)(Op23 + 2 * 4194304);        // 8 ints

    zero_cnt_kernel<<<1, 8, 0, stream>>>(cnt);
    convert_x_kernel<<<4096, 256, 0, stream>>>(x, xh, xl);
    convert_w_kernel<<<768, 256, 0, stream>>>(Wq, Wk, Wv, Wth, Wtl);
    proj_kernel<<<dim3(256, 3), 256, 0, stream>>>(xh, xl, Wth, Wtl, bq, bk, bv, Qf, Kf, Vt);
    attn6_kernel<<<512, 256, 0, stream>>>(Qf, Kf, Vt, xh, Op23, ml, cnt);
    combine_kernel<<<256, 256, 0, stream>>>(xh, Op23, ml, out);
}

// Round 9
// 260.698 us; speedup vs baseline: 1.5861x; 1.5861x over previous
//
#include <hip/hip_runtime.h>
#include <hip/hip_fp16.h>

// Softmax attention (mask is a no-op). B=4, S=4096, D=256, fp32 in/out.
// Round 9: r8's XCD work-queue serialized on one cache line (272us). Return
// to the r7-VALIDATED shell (grid 256 x 256thr, 1 block/CU, group=hw&7,
// FETCH 16.5MB) and attack r7's measured limiter (9.6K cyc/tile wall vs 3K
// busy at 1 wave/SIMD) with a 2-deep software pipeline inside the wave:
//   iter t: [wait vmcnt(8); barrier] stage_K(t+2) | QK(t+1) MFMAs
//           || softmax(t) VALU | PV(t) | barrier | stage_V(t+2)
// Counted vmcnt (T4) instead of full drains; MFMA/VALU pipes overlap.
// All r7-validated math (swapped 32x32, swizzles, Pfrag pack, epilogue)
// kept verbatim. Aux = r8's (V single-term proj validated, same absmax).

typedef _Float16 f16x8 __attribute__((ext_vector_type(8)));
typedef _Float16 f16x4 __attribute__((ext_vector_type(4)));
typedef float    f32x4 __attribute__((ext_vector_type(4)));
typedef float    f32x16 __attribute__((ext_vector_type(16)));

#define MFMA16(A, B, C) __builtin_amdgcn_mfma_f32_16x16x32_f16((A), (B), (C), 0, 0, 0)
#define MFMA32(A, B, C) __builtin_amdgcn_mfma_f32_32x32x16_f16((A), (B), (C), 0, 0, 0)

static __device__ __forceinline__ void gload16(const _Float16* g, _Float16* l) {
    __builtin_amdgcn_global_load_lds(
        (unsigned int __attribute__((address_space(1)))*)g,
        (unsigned int __attribute__((address_space(3)))*)l, 16, 0, 0);
}

static __device__ __forceinline__ unsigned packh(float a, float b) {
    union { _Float16 h[2]; unsigned u; } x;
    x.h[0] = (_Float16)a; x.h[1] = (_Float16)b;
    return x.u;
}

static __device__ __forceinline__ float fexp2(float x) {
    float r;
    asm("v_exp_f32 %0, %1" : "=v"(r) : "v"(x));
    return r;
}

// ---------------- kernel 0: x -> fp16 hi/lo, FRAGMENT-LINEAR (r7) -----------
__global__ __launch_bounds__(256) void convert_x_kernel(
    const float* __restrict__ x, _Float16* __restrict__ xh, _Float16* __restrict__ xl)
{
    int i = blockIdx.x * 256 + threadIdx.x;
    int e = i * 4;
    int row = e >> 8, k = e & 255;
    float4 v = ((const float4*)x)[i];
    float vv[4] = {v.x, v.y, v.z, v.w};
    f16x4 h, l;
#pragma unroll
    for (int j = 0; j < 4; ++j) {
        _Float16 hh = (_Float16)vv[j];
        h[j] = hh; l[j] = (_Float16)(vv[j] - (float)hh);
    }
    const int lane = (row & 15) + 16 * ((k >> 3) & 3);
    const int dst = (((row >> 4) * 8 + (k >> 5)) * 64 + lane) * 8 + (k & 7);
    *(f16x4*)(xh + dst) = h;
    *(f16x4*)(xl + dst) = l;
}

// ---------------- kernel 1: W -> W^T hi/lo, FRAGMENT-LINEAR (r7) ------------
__global__ __launch_bounds__(256) void convert_w_kernel(
    const float* __restrict__ Wq, const float* __restrict__ Wk, const float* __restrict__ Wv,
    _Float16* __restrict__ Wth, _Float16* __restrict__ Wtl)
{
    int idx = blockIdx.x * 256 + threadIdx.x;
    int mat = idx >> 16, e = idx & 65535;
    int k = e >> 8, n = e & 255;
    const float* W = (mat == 0) ? Wq : (mat == 1) ? Wk : Wv;
    float v = W[e];
    _Float16 h = (_Float16)v;
    _Float16 lo = (_Float16)(v - (float)h);
    const int lane = (n & 15) + 16 * ((k >> 3) & 3);
    const int dst = mat * 65536 + (((k >> 5) * 16 + (n >> 4)) * 64 + lane) * 8 + (k & 7);
    Wth[dst] = h;
    Wtl[dst] = lo;
}

// ---------------- kernel 2: projections (r8-validated: V single-term) -------
__global__ __launch_bounds__(256) void proj_kernel(
    const _Float16* __restrict__ xh, const _Float16* __restrict__ xl,
    const _Float16* __restrict__ Wth, const _Float16* __restrict__ Wtl,
    const float* __restrict__ bq, const float* __restrict__ bk, const float* __restrict__ bv,
    _Float16* __restrict__ Qf, _Float16* __restrict__ Kf, _Float16* __restrict__ Vt)
{
    const int mat = blockIdx.y;
    const int tid = threadIdx.x, wid = tid >> 6, lane = tid & 63;
    const int lrow = lane & 15, lgrp = lane >> 4;
    const int rb = blockIdx.x * 4 + wid;
    const int row0 = rb * 16;
    const _Float16* Wh = Wth + mat * 65536;
    const _Float16* Wl = Wtl + mat * 65536;
    const float* bias = (mat == 0) ? bq : (mat == 1) ? bk : bv;

    f32x4 acc[16];
#pragma unroll
    for (int i = 0; i < 16; ++i) acc[i] = f32x4{0.f, 0.f, 0.f, 0.f};

#pragma unroll
    for (int ks = 0; ks < 8; ++ks) {
        const size_t abase = (((size_t)rb * 8 + ks) * 64 + lane) * 8;
        f16x8 Ah = *(const f16x8*)(xh + abase);
        f16x8 Al = *(const f16x8*)(xl + abase);
#pragma unroll
        for (int nt = 0; nt < 16; ++nt) {
            const size_t bbase = ((ks * 16 + nt) * 64 + lane) * 8;
            f16x8 Bh = *(const f16x8*)(Wh + bbase);
            acc[nt] = MFMA16(Ah, Bh, acc[nt]);
            if (mat != 2) {   // V needs only hi*hi (r8-validated, same absmax)
                f16x8 Bl = *(const f16x8*)(Wl + bbase);
                acc[nt] = MFMA16(Al, Bh, acc[nt]);
                acc[nt] = MFMA16(Ah, Bl, acc[nt]);
            }
        }
    }

    const float LOG2E = 1.4426950408889634f;
#pragma unroll
    for (int nt = 0; nt < 16; ++nt) {
        const int n = nt * 16 + lrow;
        const float bb = bias[n];
        if (mat == 2) {
            const int m0 = row0 + lgrp * 4;
            f16x4 vv;
#pragma unroll
            for (int r = 0; r < 4; ++r) vv[r] = (_Float16)(acc[nt][r] + bb);
            *(f16x4*)(Vt + (size_t)n * 16384 + m0) = vv;
        } else {
            _Float16* dst = (mat == 0) ? Qf : Kf;
            const float s = (mat == 0) ? LOG2E : 1.0f;
#pragma unroll
            for (int r = 0; r < 4; ++r) {
                const int grow = row0 + lgrp * 4 + r;
                dst[(size_t)grow * 256 + n] = (_Float16)((acc[nt][r] + bb) * s);
            }
        }
    }
}

// -------- kernel 3: attn7 — r7 shell + 2-deep pipeline + counted vmcnt ------
__global__ __launch_bounds__(256) void attn7_kernel(
    const _Float16* __restrict__ Qf, const _Float16* __restrict__ Kf,
    const _Float16* __restrict__ Vt, _Float16* __restrict__ Op,
    float* __restrict__ ml)
{
    __shared__ _Float16 Kb[2][64 * 256];   // [key][d], 512B rows
    __shared__ _Float16 Vb[2][256 * 64];   // [d][key], 128B rows

    const int tid = threadIdx.x, wid = tid >> 6, lane = tid & 63;
    const int lq = lane & 31, hi = lane >> 5;

    const int hw = blockIdx.x;
    const int group = hw & 7;              // XCD under 1-block/CU round-robin
    const int qi = hw >> 3;                // [0,32)
    const int b = group >> 1, split = group & 1;
    const size_t bS = (size_t)b * 4096;
    const size_t qrow = bS + qi * 128 + wid * 32;
    const size_t k0g = bS + (size_t)split * 2048;
    const int NT = 32;

    // Q as B-fragments: lane holds Q[q=lq][d = ks*16 + hi*8 .. +8]
    f16x8 QB[16];
#pragma unroll
    for (int ks = 0; ks < 16; ++ks)
        QB[ks] = *(const f16x8*)(Qf + (qrow + lq) * 256 + ks * 16 + hi * 8);

    f32x16 Oacc[8];
#pragma unroll
    for (int i = 0; i < 8; ++i)
#pragma unroll
        for (int r = 0; r < 16; ++r) Oacc[i][r] = 0.f;
    float m_r = -1e30f, l_r = 0.f;

    auto stage_K = [&](int buf, int t) {
        const size_t krow = k0g + (size_t)t * 64;
#pragma unroll
        for (int it = 0; it < 8; ++it) {   // K: 2048 slots, 5-bit XOR swz src
            const int s = it * 256 + tid;
            const int row = s >> 5, c = s & 31;
            const int src = c ^ (row & 7) ^ (((row >> 3) & 3) << 3);
            gload16(Kf + (krow + row) * 256 + src * 8, &Kb[buf][s * 8]);
        }
    };
    auto stage_V = [&](int buf, int t) {
        const size_t krow = k0g + (size_t)t * 64;
#pragma unroll
        for (int it = 0; it < 8; ++it) {   // V^T: 2048 slots, 3-bit XOR swz
            const int s = it * 256 + tid;
            const int d = s >> 3, c = s & 7;
            gload16(Vt + (size_t)d * 16384 + krow + ((c ^ (d & 7)) * 8), &Vb[buf][s * 8]);
        }
    };

    const int kx = (lq & 7) ^ (((lq >> 3) & 3) << 3);   // K-read slot XOR

    auto qk = [&](const _Float16* K_, f32x16* sc) {
#pragma unroll
        for (int kb = 0; kb < 2; ++kb) {
#pragma unroll
            for (int r = 0; r < 16; ++r) sc[kb][r] = 0.f;
#pragma unroll
            for (int ks = 0; ks < 16; ++ks) {
                const int slot = (2 * ks + hi) ^ kx;
                f16x8 Ak = *(const f16x8*)((const char*)K_ + (kb * 32 + lq) * 512 + slot * 16);
                sc[kb] = MFMA32(Ak, QB[ks], sc[kb]);
            }
        }
    };

    // ---- prologue ----
    stage_K(0, 0); stage_V(0, 0);
    asm volatile("s_waitcnt vmcnt(0)" ::: "memory");
    __builtin_amdgcn_s_barrier();

    f32x16 scC[2], scN[2];
    qk(Kb[0], scC);                        // tile 0 scores
    stage_K(1, 1); stage_V(1, 1);          // in flight across iter 0

    const float THR = 10.0f;
    for (int t = 0; t < NT; ++t) {
        // top wait: drains V(t) and K(t+1); leaves V(t+1) (8) in flight
        if (t + 1 < NT) { asm volatile("s_waitcnt vmcnt(8)" ::: "memory"); }
        else           { asm volatile("s_waitcnt vmcnt(0)" ::: "memory"); }
        __builtin_amdgcn_s_barrier();

        if (t + 2 < NT) stage_K(t & 1, t + 2);       // Kb[t%2] is dead
        if (t + 1 < NT) qk(Kb[(t + 1) & 1], scN);    // MFMA, overlaps softmax below

        // ---- softmax(t) on scC (pure VALU) ----
        float tm[8];
#pragma unroll
        for (int j = 0; j < 8; ++j)
            tm[j] = fmaxf(fmaxf(scC[0][j], scC[0][j + 8]),
                          fmaxf(scC[1][j], scC[1][j + 8]));
#pragma unroll
        for (int s = 4; s > 0; s >>= 1)
#pragma unroll
            for (int j = 0; j < s; ++j) tm[j] = fmaxf(tm[j], tm[j + s]);
        float mx = fmaxf(tm[0], __shfl_xor(tm[0], 32));
        if (__any(mx > m_r + THR)) {
            const float mn = fmaxf(m_r, mx);
            const float scl = fexp2(m_r - mn);
            m_r = mn; l_r *= scl;
#pragma unroll
            for (int i = 0; i < 8; ++i)
#pragma unroll
                for (int r = 0; r < 16; ++r) Oacc[i][r] *= scl;
        }
        float p[32]; float rs = 0.f;
#pragma unroll
        for (int r = 0; r < 16; ++r) { p[r] = fexp2(scC[0][r] - m_r); rs += p[r]; }
#pragma unroll
        for (int r = 0; r < 16; ++r) { p[16 + r] = fexp2(scC[1][r] - m_r); rs += p[16 + r]; }
        l_r += rs + __shfl_xor(rs, 32);

        f16x8 Pfrag[4];
#pragma unroll
        for (int kb = 0; kb < 2; ++kb) {
            unsigned w[8], pw[8];
#pragma unroll
            for (int j = 0; j < 8; ++j) {
                w[j] = packh(p[kb * 16 + 2 * j], p[kb * 16 + 2 * j + 1]);
                pw[j] = __shfl_xor(w[j], 32);
            }
#pragma unroll
            for (int s = 0; s < 2; ++s) {
                unsigned f0 = hi ? pw[4 * s + 2] : w[4 * s + 0];
                unsigned f1 = hi ? pw[4 * s + 3] : w[4 * s + 1];
                unsigned f2 = hi ? w[4 * s + 2] : pw[4 * s + 0];
                unsigned f3 = hi ? w[4 * s + 3] : pw[4 * s + 1];
                union { unsigned u[4]; f16x8 f; } cvt;
                cvt.u[0] = f0; cvt.u[1] = f1; cvt.u[2] = f2; cvt.u[3] = f3;
                Pfrag[kb * 2 + s] = cvt.f;
            }
        }

        // ---- PV(t): O^T[d][q] += V^T.P from Vb[t%2] ----
        const _Float16* V_ = Vb[t & 1];
#pragma unroll
        for (int dblk = 0; dblk < 8; ++dblk) {
#pragma unroll
            for (int kstep = 0; kstep < 4; ++kstep) {
                const int slot = (kstep * 2 + hi) ^ (lq & 7);
                f16x8 Av = *(const f16x8*)((const char*)V_ + (dblk * 32 + lq) * 128 + slot * 16);
                Oacc[dblk] = MFMA32(Av, Pfrag[kstep], Oacc[dblk]);
            }
        }

        __builtin_amdgcn_s_barrier();                // all waves done with Vb[t%2]
        if (t + 2 < NT) stage_V(t & 1, t + 2);       // reuse it for V(t+2)

        scC[0] = scN[0]; scC[1] = scN[1];            // advance pipeline
    }

    // ---- epilogue: lane owns q = qrow + lq (r7-validated) ----
    _Float16* Ops = Op + (size_t)split * 4194304;
    const float inv = 1.0f / l_r;
    const size_t grow = qrow + lq;
#pragma unroll
    for (int dblk = 0; dblk < 8; ++dblk)
#pragma unroll
        for (int quad = 0; quad < 4; ++quad) {
            f16x4 o;
#pragma unroll
            for (int j = 0; j < 4; ++j) o[j] = (_Float16)(Oacc[dblk][quad * 4 + j] * inv);
            *(f16x4*)(Ops + grow * 256 + dblk * 32 + 8 * quad + 4 * hi) = o;
        }
    if (hi == 0) {
        ml[((size_t)split * 16384 + grow) * 2]     = m_r;
        ml[((size_t)split * 16384 + grow) * 2 + 1] = l_r;
    }
}

// ---------------- kernel 4: combine split-K partials (NS=2, r7-validated) ---
__global__ __launch_bounds__(256) void combine_kernel(
    const _Float16* __restrict__ Op, const float* __restrict__ ml,
    float* __restrict__ out)
{
    const int idx = blockIdx.x * 256 + threadIdx.x;
    const int row = idx >> 2, dq = (idx & 3) * 64;
    float m_s[2], l_s[2], w[2];
    float M = -1e30f;
#pragma unroll
    for (int s = 0; s < 2; ++s) {
        m_s[s] = ml[((size_t)s * 16384 + row) * 2];
        l_s[s] = ml[((size_t)s * 16384 + row) * 2 + 1];
        M = fmaxf(M, m_s[s]);
    }
    float Wsum = 0.f;
#pragma unroll
    for (int s = 0; s < 2; ++s) { w[s] = l_s[s] * fexp2(m_s[s] - M); Wsum += w[s]; }
    const float inv = 1.0f / Wsum;
#pragma unroll
    for (int s = 0; s < 2; ++s) w[s] *= inv;

#pragma unroll
    for (int ch = 0; ch < 8; ++ch) {
        const int d0 = dq + ch * 8;
        float acc[8] = {0.f, 0.f, 0.f, 0.f, 0.f, 0.f, 0.f, 0.f};
#pragma unroll
        for (int s = 0; s < 2; ++s) {
            f16x8 v = *(const f16x8*)(Op + (size_t)s * 4194304 + (size_t)row * 256 + d0);
#pragma unroll
            for (int j = 0; j < 8; ++j) acc[j] += w[s] * (float)v[j];
        }
        float4 o0 = {acc[0], acc[1], acc[2], acc[3]};
        float4 o1 = {acc[4], acc[5], acc[6], acc[7]};
        *(float4*)(out + (size_t)row * 256 + d0) = o0;
        *(float4*)(out + (size_t)row * 256 + d0 + 4) = o1;
    }
}

extern "C" void kernel_launch(void* const* d_in, const int* in_sizes, int n_in,
                              void* d_out, int out_size, void* d_ws, size_t ws_size,
                              hipStream_t stream) {
    const float* x  = (const float*)d_in[0];
    const float* Wq = (const float*)d_in[1];
    const float* bq = (const float*)d_in[2];
    const float* Wk = (const float*)d_in[3];
    const float* bk = (const float*)d_in[4];
    const float* Wv = (const float*)d_in[5];
    const float* bv = (const float*)d_in[6];
    float* out = (float*)d_out;

    // ws: xh/xl (reused as Op splits 0/1) | Qf | Kf | Vt | W | ml
    _Float16* xh  = (_Float16*)d_ws;
    _Float16* xl  = xh  + 4194304;
    _Float16* Qf  = xl  + 4194304;
    _Float16* Kf  = Qf  + 4194304;
    _Float16* Vt  = Kf  + 4194304;
    _Float16* Wth = Vt  + 4194304;
    _Float16* Wtl = Wth + 196608;
    float*    ml  = (float*)(Wtl + 196608);   // 2*16384*2 f32 = 256KB

    convert_x_kernel<<<4096, 256, 0, stream>>>(x, xh, xl);
    convert_w_kernel<<<768, 256, 0, stream>>>(Wq, Wk, Wv, Wth, Wtl);
    proj_kernel<<<dim3(256, 3), 256, 0, stream>>>(xh, xl, Wth, Wtl, bq, bk, bv, Qf, Kf, Vt);
    attn7_kernel<<<256, 256, 0, stream>>>(Qf, Kf, Vt, xh, ml);   // Op = xh/xl
    combine_kernel<<<256, 256, 0, stream>>>(xh, ml, out);
}

// Round 10
// 192.813 us; speedup vs baseline: 2.1445x; 1.3521x over previous
//
#include <hip/hip_runtime.h>
#include <hip/hip_fp16.h>

// Softmax attention (mask is a no-op). B=4, S=4096, D=256, fp32 in/out.
// Round 10:
//  (a) attn8 = r8's attn6 (2 blocks/CU, XCD self-assign queues) with the
//      queue contention bug fixed: counters padded to 256B lines + single
//      atomicAdd probe (exactly-once item handout proven; no CAS storm).
//      Controlled experiment: r8 attn verbatim otherwise.
//  (b) proj split into proj_qk (3-term) / proj_v (1-term, no xl) — removes
//      r8's runtime `if (mat != 2)` from the hot loop (it cost ~40us of aux
//      regression r7->r9 by blocking codegen specialization).

typedef _Float16 f16x8 __attribute__((ext_vector_type(8)));
typedef _Float16 f16x4 __attribute__((ext_vector_type(4)));
typedef float    f32x4 __attribute__((ext_vector_type(4)));
typedef float    f32x16 __attribute__((ext_vector_type(16)));

#define MFMA16(A, B, C) __builtin_amdgcn_mfma_f32_16x16x32_f16((A), (B), (C), 0, 0, 0)
#define MFMA32(A, B, C) __builtin_amdgcn_mfma_f32_32x32x16_f16((A), (B), (C), 0, 0, 0)

static __device__ __forceinline__ void gload16(const _Float16* g, _Float16* l) {
    __builtin_amdgcn_global_load_lds(
        (unsigned int __attribute__((address_space(1)))*)g,
        (unsigned int __attribute__((address_space(3)))*)l, 16, 0, 0);
}

static __device__ __forceinline__ unsigned packh(float a, float b) {
    union { _Float16 h[2]; unsigned u; } x;
    x.h[0] = (_Float16)a; x.h[1] = (_Float16)b;
    return x.u;
}

static __device__ __forceinline__ float fexp2(float x) {
    float r;
    asm("v_exp_f32 %0, %1" : "=v"(r) : "v"(x));
    return r;
}

// ---------------- kernel Z: zero the 8 padded work counters -----------------
__global__ void zero_cnt_kernel(int* cnt) { cnt[threadIdx.x * 64] = 0; }

// ---------------- kernel 0: x -> fp16 hi/lo, FRAGMENT-LINEAR (r7) -----------
__global__ __launch_bounds__(256) void convert_x_kernel(
    const float* __restrict__ x, _Float16* __restrict__ xh, _Float16* __restrict__ xl)
{
    int i = blockIdx.x * 256 + threadIdx.x;
    int e = i * 4;
    int row = e >> 8, k = e & 255;
    float4 v = ((const float4*)x)[i];
    float vv[4] = {v.x, v.y, v.z, v.w};
    f16x4 h, l;
#pragma unroll
    for (int j = 0; j < 4; ++j) {
        _Float16 hh = (_Float16)vv[j];
        h[j] = hh; l[j] = (_Float16)(vv[j] - (float)hh);
    }
    const int lane = (row & 15) + 16 * ((k >> 3) & 3);
    const int dst = (((row >> 4) * 8 + (k >> 5)) * 64 + lane) * 8 + (k & 7);
    *(f16x4*)(xh + dst) = h;
    *(f16x4*)(xl + dst) = l;
}

// ---------------- kernel 1: W -> W^T hi/lo, FRAGMENT-LINEAR (r7) ------------
__global__ __launch_bounds__(256) void convert_w_kernel(
    const float* __restrict__ Wq, const float* __restrict__ Wk, const float* __restrict__ Wv,
    _Float16* __restrict__ Wth, _Float16* __restrict__ Wtl)
{
    int idx = blockIdx.x * 256 + threadIdx.x;
    int mat = idx >> 16, e = idx & 65535;
    int k = e >> 8, n = e & 255;
    const float* W = (mat == 0) ? Wq : (mat == 1) ? Wk : Wv;
    float v = W[e];
    _Float16 h = (_Float16)v;
    _Float16 lo = (_Float16)(v - (float)h);
    const int lane = (n & 15) + 16 * ((k >> 3) & 3);
    const int dst = mat * 65536 + (((k >> 5) * 16 + (n >> 4)) * 64 + lane) * 8 + (k & 7);
    Wth[dst] = h;
    Wtl[dst] = lo;
}

// ------------- kernel 2a: Q/K projections, 3-term (r7 codegen) --------------
__global__ __launch_bounds__(256) void proj_qk_kernel(
    const _Float16* __restrict__ xh, const _Float16* __restrict__ xl,
    const _Float16* __restrict__ Wth, const _Float16* __restrict__ Wtl,
    const float* __restrict__ bq, const float* __restrict__ bk,
    _Float16* __restrict__ Qf, _Float16* __restrict__ Kf)
{
    const int mat = blockIdx.y;                 // 0 = Q, 1 = K
    const int tid = threadIdx.x, wid = tid >> 6, lane = tid & 63;
    const int lrow = lane & 15, lgrp = lane >> 4;
    const int rb = blockIdx.x * 4 + wid;
    const int row0 = rb * 16;
    const _Float16* Wh = Wth + mat * 65536;
    const _Float16* Wl = Wtl + mat * 65536;
    const float* bias = (mat == 0) ? bq : bk;

    f32x4 acc[16];
#pragma unroll
    for (int i = 0; i < 16; ++i) acc[i] = f32x4{0.f, 0.f, 0.f, 0.f};

#pragma unroll
    for (int ks = 0; ks < 8; ++ks) {
        const size_t abase = (((size_t)rb * 8 + ks) * 64 + lane) * 8;
        f16x8 Ah = *(const f16x8*)(xh + abase);
        f16x8 Al = *(const f16x8*)(xl + abase);
#pragma unroll
        for (int nt = 0; nt < 16; ++nt) {
            const size_t bbase = ((ks * 16 + nt) * 64 + lane) * 8;
            f16x8 Bh = *(const f16x8*)(Wh + bbase);
            f16x8 Bl = *(const f16x8*)(Wl + bbase);
            acc[nt] = MFMA16(Ah, Bh, acc[nt]);
            acc[nt] = MFMA16(Al, Bh, acc[nt]);
            acc[nt] = MFMA16(Ah, Bl, acc[nt]);
        }
    }

    const float LOG2E = 1.4426950408889634f;
    _Float16* dst = (mat == 0) ? Qf : Kf;
    const float s = (mat == 0) ? LOG2E : 1.0f;
#pragma unroll
    for (int nt = 0; nt < 16; ++nt) {
        const int n = nt * 16 + lrow;
        const float bb = bias[n];
#pragma unroll
        for (int r = 0; r < 4; ++r) {
            const int grow = row0 + lgrp * 4 + r;
            dst[(size_t)grow * 256 + n] = (_Float16)((acc[nt][r] + bb) * s);
        }
    }
}

// ------------- kernel 2b: V projection, 1-term (r8-validated precision) -----
__global__ __launch_bounds__(256) void proj_v_kernel(
    const _Float16* __restrict__ xh, const _Float16* __restrict__ Wth,
    const float* __restrict__ bv, _Float16* __restrict__ Vt)
{
    const int tid = threadIdx.x, wid = tid >> 6, lane = tid & 63;
    const int lrow = lane & 15, lgrp = lane >> 4;
    const int rb = blockIdx.x * 4 + wid;
    const int row0 = rb * 16;
    const _Float16* Wh = Wth + 2 * 65536;

    f32x4 acc[16];
#pragma unroll
    for (int i = 0; i < 16; ++i) acc[i] = f32x4{0.f, 0.f, 0.f, 0.f};

#pragma unroll
    for (int ks = 0; ks < 8; ++ks) {
        const size_t abase = (((size_t)rb * 8 + ks) * 64 + lane) * 8;
        f16x8 Ah = *(const f16x8*)(xh + abase);
#pragma unroll
        for (int nt = 0; nt < 16; ++nt) {
            const size_t bbase = ((ks * 16 + nt) * 64 + lane) * 8;
            f16x8 Bh = *(const f16x8*)(Wh + bbase);
            acc[nt] = MFMA16(Ah, Bh, acc[nt]);
        }
    }

#pragma unroll
    for (int nt = 0; nt < 16; ++nt) {
        const int n = nt * 16 + lrow;
        const float bb = bv[n];
        const int m0 = row0 + lgrp * 4;
        f16x4 vv;
#pragma unroll
        for (int r = 0; r < 4; ++r) vv[r] = (_Float16)(acc[nt][r] + bb);
        *(f16x4*)(Vt + (size_t)n * 16384 + m0) = vv;
    }
}

// -------- kernel 3: attn8 — r8's attn6 with PADDED queues, atomicAdd --------
__global__ __launch_bounds__(256, 2) void attn8_kernel(
    const _Float16* __restrict__ Qf, const _Float16* __restrict__ Kf,
    const _Float16* __restrict__ Vt, _Float16* __restrict__ Op01,
    _Float16* __restrict__ Op23, float* __restrict__ ml, int* __restrict__ cnt)
{
    __shared__ _Float16 Kb[2][32 * 256];   // [key][d] 512B rows, 16KB/buf
    __shared__ _Float16 Vb[2][256 * 32];   // [d][key] 64B rows,  16KB/buf
    __shared__ int s_item;

    const int tid = threadIdx.x, wid = tid >> 6, lane = tid & 63;
    const int lq = lane & 31, hi = lane >> 5;

    if (tid == 0) {
        int xcd;
        asm volatile("s_getreg_b32 %0, hwreg(HW_REG_XCC_ID)" : "=s"(xcd));
        xcd &= 7;
        int item = -1;
#pragma unroll 1
        for (int k = 0; k < 8; ++k) {
            const int qidx = (xcd + k) & 7;
            int v = atomicAdd(cnt + qidx * 64, 1);   // padded: 256B apart
            if (v < 64) { item = qidx * 64 + v; break; }
        }
        s_item = item;                               // provably != -1
    }
    __syncthreads();
    const int item = s_item;
    const int group = (item >> 6) * 2 + ((item & 63) >> 5);  // [0,16)
    const int qi = item & 31;
    const int b = group >> 2, split = group & 3;
    const size_t bS = (size_t)b * 4096;
    const size_t qrow = bS + qi * 128 + wid * 32;
    const size_t k0g = bS + (size_t)split * 1024;
    const int NT = 32;                                       // 1024 / 32

    f16x8 QB[16];
#pragma unroll
    for (int ks = 0; ks < 16; ++ks)
        QB[ks] = *(const f16x8*)(Qf + (qrow + lq) * 256 + ks * 16 + hi * 8);

    f32x16 Oacc[8];
#pragma unroll
    for (int i = 0; i < 8; ++i)
#pragma unroll
        for (int r = 0; r < 16; ++r) Oacc[i][r] = 0.f;
    float m_r = -1e30f, l_r = 0.f;

    auto stage = [&](int buf, int t) {
        const size_t krow = k0g + (size_t)t * 32;
#pragma unroll
        for (int it = 0; it < 4; ++it) {   // K: 1024 slots, 5-bit XOR swz src
            const int s = it * 256 + tid;
            const int row = s >> 5, c = s & 31;
            const int src = c ^ (row & 7) ^ (((row >> 3) & 3) << 3);
            gload16(Kf + (krow + row) * 256 + src * 8, &Kb[buf][s * 8]);
        }
#pragma unroll
        for (int it = 0; it < 4; ++it) {   // V^T: 1024 slots, 2-bit XOR swz
            const int s = it * 256 + tid;
            const int d = s >> 2, c = s & 3;
            gload16(Vt + (size_t)d * 16384 + krow + ((c ^ ((d >> 1) & 3)) * 8), &Vb[buf][s * 8]);
        }
    };

    stage(0, 0);
    asm volatile("s_waitcnt vmcnt(0)" ::: "memory");
    __builtin_amdgcn_s_barrier();

    const float THR = 10.0f;
    const int kx = (lq & 7) ^ (((lq >> 3) & 3) << 3);
    const int vx = (lq >> 1) & 3;
    int buf = 0;
    for (int t = 0; t < NT; ++t) {
        if (t + 1 < NT) stage(buf ^ 1, t + 1);
        const _Float16* K_ = Kb[buf];
        const _Float16* V_ = Vb[buf];

        // ---- QK: S^T[key=lq][q col], 16 MFMAs ----
        f32x16 sc;
#pragma unroll
        for (int r = 0; r < 16; ++r) sc[r] = 0.f;
#pragma unroll
        for (int ks = 0; ks < 16; ++ks) {
            const int slot = (2 * ks + hi) ^ kx;
            f16x8 Ak = *(const f16x8*)((const char*)K_ + lq * 512 + slot * 16);
            sc = MFMA32(Ak, QB[ks], sc);
        }

        // ---- per-lane online softmax ----
        float tm[8];
#pragma unroll
        for (int j = 0; j < 8; ++j) tm[j] = fmaxf(sc[j], sc[j + 8]);
#pragma unroll
        for (int s = 4; s > 0; s >>= 1)
#pragma unroll
            for (int j = 0; j < s; ++j) tm[j] = fmaxf(tm[j], tm[j + s]);
        float mx = fmaxf(tm[0], __shfl_xor(tm[0], 32));
        if (__any(mx > m_r + THR)) {
            const float mn = fmaxf(m_r, mx);
            const float scl = fexp2(m_r - mn);
            m_r = mn; l_r *= scl;
#pragma unroll
            for (int i = 0; i < 8; ++i)
#pragma unroll
                for (int r = 0; r < 16; ++r) Oacc[i][r] *= scl;
        }

        float p[16];
#pragma unroll
        for (int r = 0; r < 16; ++r) p[r] = fexp2(sc[r] - m_r);
        float ts[8];
#pragma unroll
        for (int j = 0; j < 8; ++j) ts[j] = p[j] + p[j + 8];
#pragma unroll
        for (int s = 4; s > 0; s >>= 1)
#pragma unroll
            for (int j = 0; j < s; ++j) ts[j] += ts[j + s];
        l_r += ts[0] + __shfl_xor(ts[0], 32);

        unsigned w[8], pw[8];
#pragma unroll
        for (int j = 0; j < 8; ++j) {
            w[j] = packh(p[2 * j], p[2 * j + 1]);
            pw[j] = __shfl_xor(w[j], 32);
        }
        f16x8 Pfrag[2];
#pragma unroll
        for (int s = 0; s < 2; ++s) {
            unsigned f0 = hi ? pw[4 * s + 2] : w[4 * s + 0];
            unsigned f1 = hi ? pw[4 * s + 3] : w[4 * s + 1];
            unsigned f2 = hi ? w[4 * s + 2] : pw[4 * s + 0];
            unsigned f3 = hi ? w[4 * s + 3] : pw[4 * s + 1];
            union { unsigned u[4]; f16x8 f; } cvt;
            cvt.u[0] = f0; cvt.u[1] = f1; cvt.u[2] = f2; cvt.u[3] = f3;
            Pfrag[s] = cvt.f;
        }

        // ---- PV: O^T[d][q] += V^T.P, 16 MFMAs ----
#pragma unroll
        for (int dblk = 0; dblk < 8; ++dblk) {
#pragma unroll
            for (int kstep = 0; kstep < 2; ++kstep) {
                const int slot = (kstep * 2 + hi) ^ vx;
                f16x8 Av = *(const f16x8*)((const char*)V_ + (dblk * 32 + lq) * 64 + slot * 16);
                Oacc[dblk] = MFMA32(Av, Pfrag[kstep], Oacc[dblk]);
            }
        }

        asm volatile("s_waitcnt vmcnt(0)" ::: "memory");
        __builtin_amdgcn_s_barrier();
        buf ^= 1;
    }

    // ---- epilogue ----
    _Float16* Ops = (split < 2) ? (Op01 + (size_t)split * 4194304)
                                : (Op23 + (size_t)(split - 2) * 4194304);
    const float inv = 1.0f / l_r;
    const size_t grow = qrow + lq;
#pragma unroll
    for (int dblk = 0; dblk < 8; ++dblk)
#pragma unroll
        for (int quad = 0; quad < 4; ++quad) {
            f16x4 o;
#pragma unroll
            for (int j = 0; j < 4; ++j) o[j] = (_Float16)(Oacc[dblk][quad * 4 + j] * inv);
            *(f16x4*)(Ops + grow * 256 + dblk * 32 + 8 * quad + 4 * hi) = o;
        }
    if (hi == 0) {
        ml[((size_t)split * 16384 + grow) * 2]     = m_r;
        ml[((size_t)split * 16384 + grow) * 2 + 1] = l_r;
    }
}

// ---------------- kernel 4: combine split-K partials (NS=4) -----------------
__global__ __launch_bounds__(256) void combine_kernel(
    const _Float16* __restrict__ Op01, const _Float16* __restrict__ Op23,
    const float* __restrict__ ml, float* __restrict__ out)
{
    const int idx = blockIdx.x * 256 + threadIdx.x;
    const int row = idx >> 2, dq = (idx & 3) * 64;
    float m_s[4], l_s[4], w[4];
    float M = -1e30f;
#pragma unroll
    for (int s = 0; s < 4; ++s) {
        m_s[s] = ml[((size_t)s * 16384 + row) * 2];
        l_s[s] = ml[((size_t)s * 16384 + row) * 2 + 1];
        M = fmaxf(M, m_s[s]);
    }
    float Wsum = 0.f;
#pragma unroll
    for (int s = 0; s < 4; ++s) { w[s] = l_s[s] * fexp2(m_s[s] - M); Wsum += w[s]; }
    const float inv = 1.0f / Wsum;
#pragma unroll
    for (int s = 0; s < 4; ++s) w[s] *= inv;

#pragma unroll
    for (int ch = 0; ch < 8; ++ch) {
        const int d0 = dq + ch * 8;
        float acc[8] = {0.f, 0.f, 0.f, 0.f, 0.f, 0.f, 0.f, 0.f};
#pragma unroll
        for (int s = 0; s < 4; ++s) {
            const _Float16* Op = (s < 2) ? (Op01 + (size_t)s * 4194304)
                                         : (Op23 + (size_t)(s - 2) * 4194304);
            f16x8 v = *(const f16x8*)(Op + (size_t)row * 256 + d0);
#pragma unroll
            for (int j = 0; j < 8; ++j) acc[j] += w[s] * (float)v[j];
        }
        float4 o0 = {acc[0], acc[1], acc[2], acc[3]};
        float4 o1 = {acc[4], acc[5], acc[6], acc[7]};
        *(float4*)(out + (size_t)row * 256 + d0) = o0;
        *(float4*)(out + (size_t)row * 256 + d0 + 4) = o1;
    }
}

extern "C" void kernel_launch(void* const* d_in, const int* in_sizes, int n_in,
                              void* d_out, int out_size, void* d_ws, size_t ws_size,
                              hipStream_t stream) {
    const float* x  = (const float*)d_in[0];
    const float* Wq = (const float*)d_in[1];
    const float* bq = (const float*)d_in[2];
    const float* Wk = (const float*)d_in[3];
    const float* bk = (const float*)d_in[4];
    const float* Wv = (const float*)d_in[5];
    const float* bv = (const float*)d_in[6];
    float* out = (float*)d_out;

    // ws: xh/xl (reused as Op splits 0/1) | Qf | Kf | Vt | W | ml | Op23 | cnt
    _Float16* xh  = (_Float16*)d_ws;
    _Float16* xl  = xh  + 4194304;
    _Float16* Qf  = xl  + 4194304;
    _Float16* Kf  = Qf  + 4194304;
    _Float16* Vt  = Kf  + 4194304;
    _Float16* Wth = Vt  + 4194304;
    _Float16* Wtl = Wth + 196608;
    float*    ml  = (float*)(Wtl + 196608);            // 4*16384*2 f32 = 512KB
    _Float16* Op23 = (_Float16*)((char*)ml + 524288);  // splits 2,3 (16MB)
    int*      cnt = (int*)(Op23 + 2 * 4194304);        // 8 ints, 256B apart

    zero_cnt_kernel<<<1, 8, 0, stream>>>(cnt);
    convert_x_kernel<<<4096, 256, 0, stream>>>(x, xh, xl);
    convert_w_kernel<<<768, 256, 0, stream>>>(Wq, Wk, Wv, Wth, Wtl);
    proj_qk_kernel<<<dim3(256, 2), 256, 0, stream>>>(xh, xl, Wth, Wtl, bq, bk, Qf, Kf);
    proj_v_kernel<<<256, 256, 0, stream>>>(xh, Wth, bv, Vt);
    attn8_kernel<<<512, 256, 0, stream>>>(Qf, Kf, Vt, xh, Op23, ml, cnt);
    combine_kernel<<<256, 256, 0, stream>>>(xh, Op23, ml, out);
}